// Round 9
// baseline (166.822 us; speedup 1.0000x reference)
//
#include <hip/hip_runtime.h>
#include <math.h>

#define Hdim   2048
#define HF4    512
#define MARGIN 2e-5f
#define CAPF   16384
#define PROBE0 1237
#define PROBE1 20011

// ws layout (byte offsets)
#define WS_FCNT  0
#define WS_BAD   4
#define WS_PROBE 64            // 128 floats (2 probe tokens x 64 logits)
#define WS_FLIST 1024          // CAPF ints = 64 KB
#define WS_WH    (128*1024)    // 131072 bf16 = 256 KB
#define WS_WL    (384*1024)    // 131072 bf16 = 256 KB
#define WS_NEED  (640*1024)

typedef float f32x4 __attribute__((ext_vector_type(4)));
typedef short bf8   __attribute__((ext_vector_type(8)));

// fp32 -> bf16 hi (truncated) + exact residual; RNE for the lo piece.
__device__ __forceinline__ short bf_hi(float v, float& rem) {
  const unsigned u  = __builtin_bit_cast(unsigned, v);
  const unsigned uh = u & 0xffff0000u;
  rem = v - __builtin_bit_cast(float, uh);
  return (short)(u >> 16);
}
__device__ __forceinline__ short bf_rne(float v) {
  const unsigned u = __builtin_bit_cast(unsigned, v);
  return (short)((u + 0x7fffu + ((u >> 16) & 1u)) >> 16);
}

// ---------------------------------------------------------------------------
// K0: pre-split W into fragment-ordered bf16 hi/lo arrays (same as rounds 3-8).
// f = ((ks*4 + et)*64 + lane)*8 + j ; e = et*16+(lane&15); k = ks*32+(lane>>4)*8+j
// ---------------------------------------------------------------------------
__global__ __launch_bounds__(256) void gate_prep(
    const float* __restrict__ wgt, short* __restrict__ WH, short* __restrict__ WL)
{
  const int f  = blockIdx.x * 256 + threadIdx.x;   // 0..131071
  const int c  = f >> 11;
  const int et = (f >> 9) & 3;
  const int l  = (f >> 3) & 63;
  const int j  = f & 7;
  const int e  = et * 16 + (l & 15);
  const int k  = c * 32 + (l >> 4) * 8 + j;
  const float w = wgt[(size_t)e * Hdim + k];
  float r; const short h = bf_hi(w, r);
  WH[f] = h; WL[f] = bf_rne(r);
}

// ---------------------------------------------------------------------------
// K1: BARRIER-FREE free-running split-bf16 MFMA gate.
// 256 thr = 4 fully independent waves; wave = 16 tokens x 64 experts.
// No LDS in the K-loop. x: HBM->regs via asm loads, depth-3 (P0..P3).
// W: L2->regs via asm loads (SGPR base + lane voffset), depth-2 (E/O sets).
// Per step: vmcnt(12) [drains exactly W(k),x(k)] ; sched_barrier ; split x(k);
// setprio(1); 16 MFMA; setprio(0); issue W(k+2) into just-freed set; issue
// x(k+3) into just-freed pair. In-order retirement makes the single counted
// vmcnt cover both streams (queue-traced; tails 12/12/10/0).
// In-register epilogue (R7/R8-verified).
// ---------------------------------------------------------------------------
__global__ __launch_bounds__(256, 2) void gate_main(
    const float* __restrict__ x, const short* __restrict__ WH,
    const short* __restrict__ WL, const float* __restrict__ eb,
    float* __restrict__ out, int* __restrict__ fcnt, int* __restrict__ flist,
    float* __restrict__ probelg, int T)
{
  const int t  = threadIdx.x;
  const int wv = t >> 6;
  const int ln = t & 63;
  const int tb = blockIdx.x * 64 + wv * 16;

  // x per-lane address: token tb+(ln&15), k-base (ln>>4)*8 (16x16x32 A frag)
  const char* xq = (const char*)(x + (size_t)(tb + (ln & 15)) * Hdim + (ln >> 4) * 8);
  // W: uniform SGPR base (advances 4 KB per k-step) + per-lane voffset.
  const short* whp = WH;
  const short* wlp = WL;
  const unsigned voff = (unsigned)(ln * 16);

  f32x4 acc[4];
  #pragma unroll
  for (int et = 0; et < 4; ++et) acc[et] = (f32x4)0.f;

  f32x4 P0a, P0b, P1a, P1b, P2a, P2b, P3a, P3b;          // x, depth 3
  bf8 WEh0, WEh1, WEh2, WEh3, WEl0, WEl1, WEl2, WEl3;    // W even set
  bf8 WOh0, WOh1, WOh2, WOh3, WOl0, WOl1, WOl2, WOl3;    // W odd set

#define XLOAD(D0, D1, OA, OB)                                              \
  asm volatile("global_load_dwordx4 %0, %2, off offset:" #OA "\n\t"        \
               "global_load_dwordx4 %1, %2, off offset:" #OB               \
               : "=v"(D0), "=v"(D1) : "v"(xq))

#define WLOAD(H0,H1,H2,H3,L0,L1,L2,L3)                                     \
  asm volatile(                                                            \
    "global_load_dwordx4 %0, %8, %9  offset:0\n\t"                         \
    "global_load_dwordx4 %1, %8, %9  offset:1024\n\t"                      \
    "global_load_dwordx4 %2, %8, %9  offset:2048\n\t"                      \
    "global_load_dwordx4 %3, %8, %9  offset:3072\n\t"                      \
    "global_load_dwordx4 %4, %8, %10 offset:0\n\t"                         \
    "global_load_dwordx4 %5, %8, %10 offset:1024\n\t"                      \
    "global_load_dwordx4 %6, %8, %10 offset:2048\n\t"                      \
    "global_load_dwordx4 %7, %8, %10 offset:3072"                          \
    : "=v"(H0), "=v"(H1), "=v"(H2), "=v"(H3),                              \
      "=v"(L0), "=v"(L1), "=v"(L2), "=v"(L3)                               \
    : "v"(voff), "s"(whp), "s"(wlp));                                      \
  whp += 2048; wlp += 2048;

#define WAITC(VM)                                                          \
  asm volatile("s_waitcnt vmcnt(" #VM ")" ::: "memory");                   \
  __builtin_amdgcn_sched_barrier(0);

#define COMP(XA, XB, H0,H1,H2,H3, L0,L1,L2,L3) {                                  \
    bf8 ah, al;                                                                   \
    _Pragma("unroll")                                                             \
    for (int j = 0; j < 4; ++j) { float r_;                                       \
      ah[j]     = bf_hi(XA[j], r_);  al[j]     = bf_rne(r_);                      \
      ah[j + 4] = bf_hi(XB[j], r_);  al[j + 4] = bf_rne(r_); }                    \
    __builtin_amdgcn_s_setprio(1);                                                \
    acc[0] = __builtin_amdgcn_mfma_f32_16x16x32_bf16(ah, H0, acc[0], 0, 0, 0);    \
    acc[0] = __builtin_amdgcn_mfma_f32_16x16x32_bf16(ah, L0, acc[0], 0, 0, 0);    \
    acc[0] = __builtin_amdgcn_mfma_f32_16x16x32_bf16(al, H0, acc[0], 0, 0, 0);    \
    acc[0] = __builtin_amdgcn_mfma_f32_16x16x32_bf16(al, L0, acc[0], 0, 0, 0);    \
    acc[1] = __builtin_amdgcn_mfma_f32_16x16x32_bf16(ah, H1, acc[1], 0, 0, 0);    \
    acc[1] = __builtin_amdgcn_mfma_f32_16x16x32_bf16(ah, L1, acc[1], 0, 0, 0);    \
    acc[1] = __builtin_amdgcn_mfma_f32_16x16x32_bf16(al, H1, acc[1], 0, 0, 0);    \
    acc[1] = __builtin_amdgcn_mfma_f32_16x16x32_bf16(al, L1, acc[1], 0, 0, 0);    \
    acc[2] = __builtin_amdgcn_mfma_f32_16x16x32_bf16(ah, H2, acc[2], 0, 0, 0);    \
    acc[2] = __builtin_amdgcn_mfma_f32_16x16x32_bf16(ah, L2, acc[2], 0, 0, 0);    \
    acc[2] = __builtin_amdgcn_mfma_f32_16x16x32_bf16(al, H2, acc[2], 0, 0, 0);    \
    acc[2] = __builtin_amdgcn_mfma_f32_16x16x32_bf16(al, L2, acc[2], 0, 0, 0);    \
    acc[3] = __builtin_amdgcn_mfma_f32_16x16x32_bf16(ah, H3, acc[3], 0, 0, 0);    \
    acc[3] = __builtin_amdgcn_mfma_f32_16x16x32_bf16(ah, L3, acc[3], 0, 0, 0);    \
    acc[3] = __builtin_amdgcn_mfma_f32_16x16x32_bf16(al, H3, acc[3], 0, 0, 0);    \
    acc[3] = __builtin_amdgcn_mfma_f32_16x16x32_bf16(al, L3, acc[3], 0, 0, 0);    \
    __builtin_amdgcn_s_setprio(0);                                                \
  }

#define CE(XA,XB) COMP(XA,XB, WEh0,WEh1,WEh2,WEh3, WEl0,WEl1,WEl2,WEl3)
#define CO(XA,XB) COMP(XA,XB, WOh0,WOh1,WOh2,WOh3, WOl0,WOl1,WOl2,WOl3)
#define WE_ WLOAD(WEh0,WEh1,WEh2,WEh3, WEl0,WEl1,WEl2,WEl3)
#define WO_ WLOAD(WOh0,WOh1,WOh2,WOh3, WOl0,WOl1,WOl2,WOl3)

  // prologue (issue order defines the vmcnt queue): W(0),x(0),W(1),x(1),x(2)
  WE_;                                   // W(0) -> E   (8 ops)
  XLOAD(P0a, P0b, 0, 16);                // x(0)        (2)
  WO_;                                   // W(1) -> O   (8)
  XLOAD(P1a, P1b, 128, 144);             // x(1)        (2)
  XLOAD(P2a, P2b, 256, 272);             // x(2)        (2)   -> 22 in flight

  #pragma unroll 1
  for (int it = 0; it < 15; ++it) {      // steps 0..59
    WAITC(12); CE(P0a, P0b); WE_; XLOAD(P3a, P3b, 384, 400);
    WAITC(12); CO(P1a, P1b); WO_; XLOAD(P0a, P0b, 512, 528);
    WAITC(12); CE(P2a, P2b); WE_; XLOAD(P1a, P1b, 640, 656);
    WAITC(12); CO(P3a, P3b); WO_; XLOAD(P2a, P2b, 768, 784);
    xq += 512;
  }
  // tail: steps 60..63
  WAITC(12); CE(P0a, P0b); WE_; XLOAD(P3a, P3b, 384, 400);   // W(62), x(63)
  WAITC(12); CO(P1a, P1b); WO_;                               // W(63)
  WAITC(10); CE(P2a, P2b);
  WAITC(0);  CO(P3a, P3b);
#undef WE_
#undef WO_
#undef CE
#undef CO
#undef COMP
#undef WAITC
#undef WLOAD
#undef XLOAD

  // ---- fully in-register epilogue (R7/R8-verified) ----
  // lane = (g, c): g = ln>>4, c = ln&15; row = g*4+r; expert e = et*16+c.
  const int c = ln & 15, g = ln >> 4;
  float bias4[4];
  #pragma unroll
  for (int et = 0; et < 4; ++et) bias4[et] = eb[et * 16 + c];

  #pragma unroll
  for (int r = 0; r < 4; ++r) {
    const int gt = tb + g * 4 + r;
    const float z0 = acc[0][r], z1 = acc[1][r], z2 = acc[2][r], z3 = acc[3][r];
    if (gt == PROBE0) { probelg[c]      = z0; probelg[16 + c] = z1;
                        probelg[32 + c] = z2; probelg[48 + c] = z3; }
    if (gt == PROBE1) { probelg[64 + c]  = z0; probelg[80 + c]  = z1;
                        probelg[96 + c]  = z2; probelg[112 + c] = z3; }
    float m = fmaxf(fmaxf(z0, z1), fmaxf(z2, z3));
    #pragma unroll
    for (int off = 1; off < 16; off <<= 1) m = fmaxf(m, __shfl_xor(m, off, 64));
    const float p0 = expf(z0 - m), p1 = expf(z1 - m);
    const float p2 = expf(z2 - m), p3 = expf(z3 - m);
    float Zs = (p0 + p1) + (p2 + p3);
    #pragma unroll
    for (int off = 1; off < 16; off <<= 1) Zs += __shfl_xor(Zs, off, 64);
    const float inv = 1.f / Zs;
    const float s0 = p0 * inv, s1 = p1 * inv, s2 = p2 * inv, s3 = p3 * inv;
    float b0 = s0 + bias4[0], b1 = s1 + bias4[1];
    float b2 = s2 + bias4[2], b3 = s3 + bias4[3];
    float prev = 0.f, gmin = 1e30f, mys = 0.f;
    int myi = 0;
    #pragma unroll
    for (int r9 = 0; r9 < 9; ++r9) {
      float v = b0; int ie = 0;                    // in-lane argmax (ties->lower et)
      if (b1 > v) { v = b1; ie = 1; }
      if (b2 > v) { v = b2; ie = 2; }
      if (b3 > v) { v = b3; ie = 3; }
      int idx = ie * 16 + c;
      #pragma unroll
      for (int off = 1; off < 16; off <<= 1) {     // 16-lane argmax, ties->lower idx
        const float ov = __shfl_xor(v, off, 64);
        const int   oi = __shfl_xor(idx, off, 64);
        if (ov > v || (ov == v && oi < idx)) { v = ov; idx = oi; }
      }
      if (r9) gmin = fminf(gmin, prev - v);
      prev = v;
      if (r9 < 8) {
        const int oe = idx >> 4, oc = idx & 15;
        const float cand = oe == 0 ? s0 : oe == 1 ? s1 : oe == 2 ? s2 : s3;
        const float sv = __shfl(cand, g * 16 + oc, 64);   // winner's orig score
        if (c == r9) { myi = idx; mys = sv; }
        if (c == oc) {                              // eliminate winner
          if (oe == 0) b0 = -1e30f;
          else if (oe == 1) b1 = -1e30f;
          else if (oe == 2) b2 = -1e30f;
          else b3 = -1e30f;
        }
      }
    }
    float wsum = (c < 8) ? mys : 0.f;
    #pragma unroll
    for (int off = 1; off < 16; off <<= 1) wsum += __shfl_xor(wsum, off, 64);
    if (c < 8) {
      out[(size_t)gt * 8 + c] = (float)myi;                    // indices as float
      out[(size_t)T * 8 + (size_t)gt * 8 + c] = mys / (wsum + 1e-20f);
    }
    if (c == 0 && gmin < MARGIN) {
      const int pos = atomicAdd(fcnt, 1);
      if (pos < CAPF) flist[pos] = gt;
    }
  }
}

// ---------------------------------------------------------------------------
// K2: structural self-check: 2 blocks x 256 thr, each recomputes one probe
// token's 64 logits in fp32 VALU.
// ---------------------------------------------------------------------------
__global__ __launch_bounds__(256) void gate_check(
    const float* __restrict__ x, const float* __restrict__ wgt,
    const float* __restrict__ probelg, const int* __restrict__ fcnt,
    int* __restrict__ allbad)
{
  __shared__ float part[64][4];
  const int p = blockIdx.x;
  const int P = p ? PROBE1 : PROBE0;
  const int t = threadIdx.x, e = t >> 2, q = t & 3;
  const float4* xr = (const float4*)(x + (size_t)P * Hdim);
  const float4* wr = (const float4*)(wgt + (size_t)e * Hdim);
  float a = 0.f, b = 0.f, c = 0.f, d = 0.f;
  for (int i = 0; i < 128; ++i) {
    const int f4 = i * 4 + q;
    const float4 xv = xr[f4], wv = wr[f4];
    a = fmaf(xv.x, wv.x, a); b = fmaf(xv.y, wv.y, b);
    c = fmaf(xv.z, wv.z, c); d = fmaf(xv.w, wv.w, d);
  }
  part[e][q] = (a + b) + (c + d);
  __syncthreads();
  if (q == 0) {
    const float z = part[e][0] + part[e][1] + part[e][2] + part[e][3];
    if (fabsf(z - probelg[p * 64 + e]) > 0.05f) *allbad = 1;
  }
  if (t == 0 && p == 0 && *fcnt > CAPF) *allbad = 1;
}

// ---------------------------------------------------------------------------
// K3: fp64 fixup. Normal: flagged near-tie tokens. allbad: ALL tokens.
// ---------------------------------------------------------------------------
__global__ __launch_bounds__(256) void gate_fix(
    const float* __restrict__ x, const float* __restrict__ wgt,
    const float* __restrict__ eb, float* __restrict__ out,
    const int* __restrict__ fcnt, const int* __restrict__ flist,
    const int* __restrict__ allbad, int T)
{
  __shared__ float4 xl[4 * HF4];           // 32 KB
  __shared__ double part[4][64][4];        // 8 KB
  __shared__ int tks[4];
  const int bad = *allbad;
  int n = bad ? T : *fcnt;
  if (n <= 0) return;
  if (!bad && n > CAPF) n = CAPF;
  const int nb = (n + 3) >> 2;
  const int t = threadIdx.x;
  for (int b = blockIdx.x; b < nb; b += gridDim.x) {
    if (t < 4) {
      const int li = b * 4 + t;
      const int ci = li < n ? li : n - 1;      // clamp: benign duplicate work
      tks[t] = bad ? ci : flist[ci];
    }
    __syncthreads();
    {
      const int m = t >> 6, l2 = t & 63;
      const float4* src = (const float4*)x + (size_t)tks[m] * HF4;
      #pragma unroll
      for (int ii = 0; ii < 8; ++ii) xl[m * HF4 + ii * 64 + l2] = src[ii * 64 + l2];
    }
    __syncthreads();
    const int e = t >> 2, q = t & 3;          // 64 experts x 4 k-quarters
    double acc[4] = {0.0, 0.0, 0.0, 0.0};
    const float4* w4 = (const float4*)wgt + (size_t)e * HF4;
    for (int c = 0; c < 128; ++c) {
      const int f4 = c * 4 + q;
      const float4 wvv = w4[f4];
      #pragma unroll
      for (int m = 0; m < 4; ++m) {
        const float4 xv = xl[m * HF4 + f4];
        acc[m] += (double)xv.x * (double)wvv.x + (double)xv.y * (double)wvv.y
                + (double)xv.z * (double)wvv.z + (double)xv.w * (double)wvv.w;
      }
    }
    #pragma unroll
    for (int m = 0; m < 4; ++m) part[m][e][q] = acc[m];
    __syncthreads();
    {
      const int m = t >> 6, ln = t & 63;      // wave m -> token m, lane = expert
      const double z = part[m][ln][0] + part[m][ln][1] + part[m][ln][2] + part[m][ln][3];
      double mx = z;
      #pragma unroll
      for (int off = 32; off; off >>= 1) mx = fmax(mx, __shfl_xor(mx, off, 64));
      const double p = exp(z - mx);
      double Zs = p;
      #pragma unroll
      for (int off = 32; off; off >>= 1) Zs += __shfl_xor(Zs, off, 64);
      const double sco = p / Zs;
      double bsw = sco + (double)eb[ln];
      double mys = 0.0;
      int myi = 0;
      #pragma unroll
      for (int r = 0; r < 8; ++r) {
        double v = bsw;
        int idx = ln;
        #pragma unroll
        for (int off = 32; off; off >>= 1) {
          const double ov = __shfl_xor(v, off, 64);
          const int   oi = __shfl_xor(idx, off, 64);
          if (ov > v || (ov == v && oi < idx)) { v = ov; idx = oi; }
        }
        const double sv = __shfl(sco, idx, 64);
        if (ln == r)  { myi = idx; mys = sv; }
        if (ln == idx) bsw = -1.0e300;
      }
      double wsum = (ln < 8) ? mys : 0.0;
      #pragma unroll
      for (int off = 32; off; off >>= 1) wsum += __shfl_xor(wsum, off, 64);
      const int gt = tks[m];
      if (ln < 8) {
        out[(size_t)gt * 8 + ln] = (float)myi;
        out[(size_t)T * 8 + (size_t)gt * 8 + ln] = (float)(mys / (wsum + 1e-20));
      }
    }
    __syncthreads();
  }
}

extern "C" void kernel_launch(void* const* d_in, const int* in_sizes, int n_in,
                              void* d_out, int out_size, void* d_ws, size_t ws_size,
                              hipStream_t stream) {
  const float* x   = (const float*)d_in[0];
  const float* wgt = (const float*)d_in[1];
  const float* eb  = (const float*)d_in[2];
  float* out = (float*)d_out;
  const int T = in_sizes[0] / Hdim;          // 32768
  char* ws = (char*)d_ws;
  int*   fcnt    = (int*)(ws + WS_FCNT);
  int*   bad     = (int*)(ws + WS_BAD);
  float* probelg = (float*)(ws + WS_PROBE);
  int*   flist   = (int*)(ws + WS_FLIST);
  short* WH      = (short*)(ws + WS_WH);
  short* WL      = (short*)(ws + WS_WL);

  if (ws_size < WS_NEED) {                   // tiny-ws fallback: full fp64 path
    hipMemsetAsync(ws, 0, 8, stream);
    hipMemsetAsync(ws + WS_BAD, 1, 1, stream);   // allbad != 0
    hipLaunchKernelGGL(gate_fix, dim3(256), dim3(256), 0, stream,
                       x, wgt, eb, out, fcnt, flist, bad, T);
    return;
  }
  hipMemsetAsync(ws, 0, 8, stream);          // fcnt = 0, allbad = 0
  hipLaunchKernelGGL(gate_prep, dim3(512), dim3(256), 0, stream, wgt, WH, WL);
  hipLaunchKernelGGL(gate_main, dim3(T / 64), dim3(256), 0, stream,
                     x, WH, WL, eb, out, fcnt, flist, probelg, T);
  hipLaunchKernelGGL(gate_check, dim3(2), dim3(256), 0, stream,
                     x, wgt, probelg, fcnt, bad);
  hipLaunchKernelGGL(gate_fix, dim3(256), dim3(256), 0, stream,
                     x, wgt, eb, out, fcnt, flist, bad, T);
}